// Round 12
// baseline (84.777 us; speedup 1.0000x reference)
//
#include <hip/hip_runtime.h>

#define BB 8
#define TT 512
#define DD 64
#define S_SCALE 1.2011224087864498f   // sqrt(log2(e)); exp(-u^2) = exp2(-(S*u)^2)

typedef float v2f __attribute__((ext_vector_type(2)));
typedef _Float16 h8 __attribute__((ext_vector_type(8)));
typedef _Float16 v2h __attribute__((ext_vector_type(2)));

static __device__ __forceinline__ float fast_exp2(float v) {
#if __has_builtin(__builtin_amdgcn_exp2f)
    return __builtin_amdgcn_exp2f(v);
#else
    return exp2f(v);
#endif
}
static __device__ __forceinline__ float fast_rcp(float v) {
#if __has_builtin(__builtin_amdgcn_rcpf)
    return __builtin_amdgcn_rcpf(v);
#else
    return 1.0f / v;
#endif
}
static __device__ __forceinline__ v2f pk_fma(v2f a, v2f b, v2f c) {
#if __has_builtin(__builtin_elementwise_fma)
    return __builtin_elementwise_fma(a, b, c);
#else
    return a * b + c;
#endif
}
static __device__ __forceinline__ v2f cvt2(v2h h) {
    return __builtin_convertvector(h, v2f);
}

// ------- kernel 1: v = x@W^T + b ; f16 S*x, f16 v, f32 v -------
__global__ __launch_bounds__(256) void rbf_pre(
    const float* __restrict__ x, const float* __restrict__ W,
    const float* __restrict__ bias,
    _Float16* __restrict__ xh, _Float16* __restrict__ vh,
    float* __restrict__ vv)
{
    const int t = threadIdx.x;
    const int w = t >> 6, l = t & 63;
    const int row = blockIdx.x * 4 + w;
    const float* xr = x + (size_t)row * DD;
    const float* wr = W + (size_t)l * DD;
    float acc = bias[l];
    #pragma unroll
    for (int d = 0; d < DD; d += 4) {
        float4 xv = *(const float4*)(xr + d);
        float4 wv = *(const float4*)(wr + d);
        acc = fmaf(xv.x, wv.x, acc); acc = fmaf(xv.y, wv.y, acc);
        acc = fmaf(xv.z, wv.z, acc); acc = fmaf(xv.w, wv.w, acc);
    }
    xh[(size_t)row * DD + l] = (_Float16)(xr[l] * S_SCALE);
    vh[(size_t)row * DD + l] = (_Float16)acc;
    vv[(size_t)row * DD + l] = acc;
}

// ------- tile body: 2 i-rows (per wave) x 64 j x 64 d, optional mirror -------
// Lazy 2-element f16->f32 conversion of xj/vj keeps live f32 state small
// (targeting <=64 VGPR so 8 waves/EU are eligible).
template <bool MIRROR>
static __device__ __forceinline__ void tile_compute(
    const _Float16* xls, const _Float16* vls,
    const float* xis, const float* vis,
    float* __restrict__ orow0, float* cbuf, int l, int wau)
{
    v2f nr[2][2], nc[2][2], dn[2];
    #pragma unroll
    for (int r = 0; r < 2; ++r) {
        nr[r][0] = (v2f){0.f, 0.f}; nr[r][1] = (v2f){0.f, 0.f};
        nc[r][0] = (v2f){0.f, 0.f}; nc[r][1] = (v2f){0.f, 0.f};
        dn[r]    = (v2f){0.f, 0.f};
    }

    #pragma unroll
    for (int c = 0; c < 8; ++c) {
        h8 xjh = *(const h8*)(xls + l * 72 + c * 8);   // dense ds_read_b128
        h8 vjh = *(const h8*)(vls + l * 72 + c * 8);
        const v2h* xjp = (const v2h*)&xjh;             // lane-local sub-vectors
        const v2h* vjp = (const v2h*)&vjh;
        #pragma unroll
        for (int r = 0; r < 2; ++r) {
            const v2f* xi2 = (const v2f*)(xis + (wau * 2 + r) * DD + c * 8); // bcast
            const v2f* vi2 = (const v2f*)(vis + (wau * 2 + r) * DD + c * 8); // bcast
            #pragma unroll
            for (int q = 0; q < 4; ++q) {
                v2f u = xi2[q] - cvt2(xjp[q]);
                u *= u;
                v2f e = {fast_exp2(-u.x), fast_exp2(-u.y)};
                nr[r][q & 1] = pk_fma(e, vi2[q], nr[r][q & 1]);
                if (MIRROR) nc[r][q & 1] = pk_fma(e, cvt2(vjp[q]), nc[r][q & 1]);
                dn[r] += e;
            }
        }
    }

    #pragma unroll
    for (int r = 0; r < 2; ++r) {
        float rd = fast_rcp(dn[r].x + dn[r].y);
        v2f sr = nr[r][0] + nr[r][1];
        orow0[(size_t)r * TT + l] = (sr.x + sr.y) * rd;   // coalesced 256 B
        if (MIRROR) {
            v2f sc = nc[r][0] + nc[r][1];
            cbuf[l * 12 + wau * 2 + r] = (sc.x + sc.y) * rd;
        }
    }
}

// ------- kernel 2: symmetric pairwise tiles, 8 i x 64 j, 288/batch -------
// idx<64: diagonal band (no mirror); else triangle walk (mirror writes
// out[j, i0..i0+8) too). launch_bounds(256,8) -> 64-VGPR cap -> 8 waves/EU
// eligible; LDS 23.5 KB caps residency at 6 blocks = 24 waves/CU.
__global__ __launch_bounds__(256, 8) void rbf_sym(
    const float* __restrict__ x,
    const _Float16* __restrict__ xh, const _Float16* __restrict__ vh,
    const float* __restrict__ vv, float* __restrict__ out)
{
    const int bid = blockIdx.x;
    const int b = bid / 288;
    int idx = bid - b * 288;
    int ti, jt, isA;
    if (idx < 64) { jt = idx >> 3; ti = 8 * jt + (idx & 7); isA = 0; }
    else {
        int k = idx - 64, t = 1;
        while (k >= 8 * t) { k -= 8 * t; ++t; }   // <=7 scalar iters
        jt = t; ti = k; isA = 1;
    }
    const int i0 = ti * 8, j0 = jt * 64;

    const int tid = threadIdx.x;
    const int w = tid >> 6, l = tid & 63;
    const int wau = __builtin_amdgcn_readfirstlane(w);

    __shared__ __align__(16) _Float16 xls[64 * 72];  // f16 S*xj tile (144 B rows)
    __shared__ __align__(16) _Float16 vls[64 * 72];  // f16 vj tile
    __shared__ __align__(16) float xis[8 * DD];      // f32 S*xi strip (bcast reads)
    __shared__ __align__(16) float vis[8 * DD];      // f32 vi strip
    __shared__ float cbuf[64 * 12];                  // mirror [j][iloc 0..7]

    // ---- stage j-tiles: 8 KB each, coalesced uint4 ----
    {
        const uint4* xsrc = (const uint4*)(xh + ((size_t)b * TT + j0) * DD);
        const uint4* vsrc = (const uint4*)(vh + ((size_t)b * TT + j0) * DD);
        #pragma unroll
        for (int u = 0; u < 2; ++u) {
            int g = u * 256 + tid;          // 512 uint4 granules per array
            int r = g >> 3, c = g & 7;
            *(uint4*)(xls + r * 72 + c * 8) = xsrc[g];
            *(uint4*)(vls + r * 72 + c * 8) = vsrc[g];
        }
        // ---- stage i-strips: tid<128 -> S*x (f32), else -> v (f32) ----
        int g = tid & 127;                  // 128 f4 granules = 8 rows x 16
        int r = g >> 4, c4 = (g & 15) * 4;
        if (tid < 128) {
            float4 v = *(const float4*)(x + ((size_t)(b * TT + i0 + r)) * DD + c4);
            v.x *= S_SCALE; v.y *= S_SCALE; v.z *= S_SCALE; v.w *= S_SCALE;
            *(float4*)(xis + r * DD + c4) = v;
        } else {
            *(float4*)(vis + r * DD + c4) =
                *(const float4*)(vv + ((size_t)(b * TT + i0 + r)) * DD + c4);
        }
    }
    __syncthreads();

    float* outb  = out + (size_t)b * TT * TT;
    float* orow0 = outb + (size_t)(i0 + wau * 2) * TT + j0;

    if (isA) tile_compute<true >(xls, vls, xis, vis, orow0, cbuf, l, wau);
    else     tile_compute<false>(xls, vls, xis, vis, orow0, cbuf, l, wau);

    __syncthreads();
    if (isA && tid < 128) {
        // flush mirror: out[j0+j][i0 .. i0+8), 16-B aligned float4 per thread
        int j = tid >> 1, qf = (tid & 1) * 4;
        float4 cv = *(const float4*)(cbuf + j * 12 + qf);
        *(float4*)(outb + (size_t)(j0 + j) * TT + i0 + qf) = cv;
    }
}

extern "C" void kernel_launch(void* const* d_in, const int* in_sizes, int n_in,
                              void* d_out, int out_size, void* d_ws, size_t ws_size,
                              hipStream_t stream) {
    const float* x    = (const float*)d_in[0];
    const float* W    = (const float*)d_in[1];
    const float* bias = (const float*)d_in[2];
    float* out        = (float*)d_out;

    _Float16* xh = (_Float16*)d_ws;                       // 0.5 MB
    _Float16* vh = (_Float16*)((char*)d_ws + (1 << 19));  // 0.5 MB
    float*    vv = (float*)((char*)d_ws + (1 << 20));     // 1 MB

    rbf_pre<<<BB * TT / 4, 256, 0, stream>>>(x, W, bias, xh, vh, vv);
    rbf_sym<<<BB * 288, 256, 0, stream>>>(x, xh, vh, vv, out);
}